// Round 6
// baseline (617.377 us; speedup 1.0000x reference)
//
#include <hip/hip_runtime.h>
#include <hip/hip_bf16.h>

#define RR 3
#define NN 20000
#define EE 320000
#define FF 256
#define HH 8
#define OO 64
#define DD 512

typedef _Float16 half8 __attribute__((ext_vector_type(8)));
typedef float f32x4 __attribute__((ext_vector_type(4)));

__device__ __forceinline__ float2 up2(unsigned int u){
    union { unsigned int u; _Float16 h[2]; } t; t.u = u;
    return make_float2((float)t.h[0], (float)t.h[1]);
}

__device__ __forceinline__ void gl_lds16(const void* g, void* l){
    __builtin_amdgcn_global_load_lds(
        (const __attribute__((address_space(1))) unsigned int*)g,
        (__attribute__((address_space(3))) unsigned int*)l, 16, 0, 0);
}

// ---------- transpose+split W -> Wt[r][d][k] fp16 hi/lo, transpose W1 -> W1t[j][i] fp16 ----------
__global__ void prep_weights_kernel(const float* __restrict__ W, const float* __restrict__ W1,
                                    _Float16* __restrict__ Wthi, _Float16* __restrict__ Wtlo,
                                    _Float16* __restrict__ W1t){
    int idx = blockIdx.x * blockDim.x + threadIdx.x;
    const int c1 = RR * DD * FF;
    if (idx < c1){
        int r = idx / (DD * FF);
        int rem = idx % (DD * FF);
        int d = rem / FF;
        int k = rem % FF;
        float v = W[(size_t)r * FF * DD + (size_t)k * DD + d];
        _Float16 h = (_Float16)v;
        Wthi[idx] = h;
        Wtlo[idx] = (_Float16)(v - (float)h);
    } else if (idx < c1 + OO * DD){
        int idx2 = idx - c1;
        int j = idx2 / DD;
        int i = idx2 % DD;
        W1t[idx2] = (_Float16)W1[(size_t)i * OO + j];
    }
}

// ---------------- CSR build ----------------
__global__ void hist_kernel(const int* __restrict__ dst, int* __restrict__ counts){
    int idx = blockIdx.x * blockDim.x + threadIdx.x;
    if (idx >= RR * EE) return;
    int r = idx / EE;
    atomicAdd(&counts[r * NN + dst[idx]], 1);
}

// 20 contiguous elements per thread; one block-scan round total
__global__ __launch_bounds__(1024) void scan_kernel(int* __restrict__ counts,  // also cursor (aliased)
                            int* __restrict__ row_ptr){
    int r = blockIdx.x;
    int tid = threadIdx.x, lane = tid & 63, wid = tid >> 6;
    __shared__ int wsum[16];
    const int PER = 20;
    int base = tid * PER;
    int* cr = counts + r * NN;
    int vals[PER];
    int sum = 0;
    #pragma unroll
    for (int i = 0; i < PER; i++){
        int idx = base + i;
        int v = (idx < NN) ? cr[idx] : 0;
        vals[i] = v;
        sum += v;
    }
    int inc = sum;
    #pragma unroll
    for (int off = 1; off < 64; off <<= 1){
        int t = __shfl_up(inc, off, 64);
        if (lane >= off) inc += t;
    }
    if (lane == 63) wsum[wid] = inc;
    __syncthreads();
    if (wid == 0 && lane < 16){
        int s = wsum[lane];
        int si = s;
        #pragma unroll
        for (int off = 1; off < 16; off <<= 1){
            int t = __shfl_up(si, off, 16);
            if (lane >= off) si += t;
        }
        wsum[lane] = si - s;   // exclusive wave offset
    }
    __syncthreads();
    int run = (inc - sum) + wsum[wid];
    if (tid == 0) row_ptr[r * (NN + 1)] = 0;
    #pragma unroll
    for (int i = 0; i < PER; i++){
        int idx = base + i;
        if (idx < NN){
            cr[idx] = run;                       // cursor = exclusive start
            run += vals[i];
            row_ptr[r * (NN + 1) + idx + 1] = run;
        }
    }
}

__global__ void scatter_kernel(const int* __restrict__ src, const int* __restrict__ dst,
                               int* __restrict__ cursor, int* __restrict__ ssrc){
    int idx = blockIdx.x * blockDim.x + threadIdx.x;
    if (idx >= RR * EE) return;
    int r = idx / EE;
    int pos = atomicAdd(&cursor[r * NN + dst[idx]], 1);
    ssrc[(size_t)r * EE + pos] = src[idx];
}

// ------- h = feats @ W (128x256 LDS-tiled MFMA, 2-pass B-split fp16) + fused el/er -------
#define BM 128
#define BN 256
#define BK 32
#define APAD 36   // fp32 row stride in LDS (32 + 4 pad)

__global__ __launch_bounds__(256) void gemm_h_kernel(
        const float* __restrict__ feats,
        const _Float16* __restrict__ Wthi, const _Float16* __restrict__ Wtlo,
        const float* __restrict__ al, const float* __restrict__ ar,
        _Float16* __restrict__ Hout, float* __restrict__ elo, float* __restrict__ ero){
    __shared__ float    sA[BM * APAD];
    __shared__ _Float16 sBh[BN * BK];
    __shared__ _Float16 sBl[BN * BK];
    int r = blockIdx.z;
    int m0 = blockIdx.x * BM;
    int n0 = blockIdx.y * BN;
    const float* A = feats + (size_t)r * NN * FF;
    const _Float16* Bh = Wthi + (size_t)r * DD * FF;
    const _Float16* Bl = Wtlo + (size_t)r * DD * FF;
    int t = threadIdx.x;
    int lane = t & 63;
    int wave = t >> 6;
    int wr = wave >> 1, wc = wave & 1;   // wave tile: rows wr*64, cols wc*128
    int l15 = lane & 15;
    int kg = (lane >> 4) * 8;

    f32x4 acc[4][8];
    #pragma unroll
    for (int mi = 0; mi < 4; mi++)
        #pragma unroll
        for (int ni = 0; ni < 8; ni++)
            acc[mi][ni] = (f32x4){0.f, 0.f, 0.f, 0.f};

    int arr[4];
    #pragma unroll
    for (int i = 0; i < 4; i++){
        int row = (t + i * 256) >> 3;
        int gr = m0 + row;
        arr[i] = (gr < NN) ? gr : (NN - 1);
    }

    for (int k0 = 0; k0 < FF; k0 += BK){
        __syncthreads();
        #pragma unroll
        for (int i = 0; i < 4; i++){
            int c = t + i * 256;
            int row = c >> 3, kc = c & 7;
            float4 v = *reinterpret_cast<const float4*>(A + (size_t)arr[i] * FF + k0 + kc * 4);
            *reinterpret_cast<float4*>(&sA[row * APAD + kc * 4]) = v;
        }
        #pragma unroll
        for (int i = 0; i < 4; i++){
            int c = t + i * 256;
            int row = c >> 2, kc = c & 3;
            size_t goff = (size_t)(n0 + row) * FF + k0 + kc * 8;
            gl_lds16(Bh + goff, &sBh[c * 8]);
            gl_lds16(Bl + goff, &sBl[c * 8]);
        }
        __syncthreads();

        half8 af[4];
        #pragma unroll
        for (int mi = 0; mi < 4; mi++){
            const float* ap = &sA[(wr * 64 + mi * 16 + l15) * APAD + kg];
            float4 x = *reinterpret_cast<const float4*>(ap);
            float4 y = *reinterpret_cast<const float4*>(ap + 4);
            af[mi][0] = (_Float16)x.x; af[mi][1] = (_Float16)x.y;
            af[mi][2] = (_Float16)x.z; af[mi][3] = (_Float16)x.w;
            af[mi][4] = (_Float16)y.x; af[mi][5] = (_Float16)y.y;
            af[mi][6] = (_Float16)y.z; af[mi][7] = (_Float16)y.w;
        }
        #pragma unroll
        for (int ni = 0; ni < 8; ni++){
            int cb = (wc * 128 + ni * 16 + l15) * BK + kg;
            half8 bh = *reinterpret_cast<const half8*>(&sBh[cb]);
            half8 bl = *reinterpret_cast<const half8*>(&sBl[cb]);
            #pragma unroll
            for (int mi = 0; mi < 4; mi++){
                acc[mi][ni] = __builtin_amdgcn_mfma_f32_16x16x32_f16(af[mi], bh, acc[mi][ni], 0, 0, 0);
                acc[mi][ni] = __builtin_amdgcn_mfma_f32_16x16x32_f16(af[mi], bl, acc[mi][ni], 0, 0, 0);
            }
        }
    }

    _Float16* Hr = Hout + (size_t)r * NN * DD;
    #pragma unroll
    for (int mi = 0; mi < 4; mi++){
        #pragma unroll
        for (int g = 0; g < 4; g++){
            int row = m0 + wr * 64 + mi * 16 + (lane >> 4) * 4 + g;
            if (row < NN){
                #pragma unroll
                for (int ni = 0; ni < 8; ni++){
                    int col = n0 + wc * 128 + ni * 16 + l15;
                    Hr[(size_t)row * DD + col] = (_Float16)acc[mi][ni][g];
                }
            }
        }
    }

    // ---- fused el/er: this wave's 128 cols span heads hh0, hh0+1 ----
    int hh0 = blockIdx.y * 4 + wc * 2;
    const float* alp = al + r * DD + hh0 * OO;
    const float* arp = ar + r * DD + hh0 * OO;
    float alv[8], arv[8];
    #pragma unroll
    for (int ni = 0; ni < 8; ni++){
        int off2 = (ni >> 2) * OO + (ni & 3) * 16 + l15;
        alv[ni] = alp[off2];
        arv[ni] = arp[off2];
    }
    float* elr_ = elo + (size_t)r * NN * HH;
    float* err_ = ero + (size_t)r * NN * HH;
    #pragma unroll
    for (int mi = 0; mi < 4; mi++){
        #pragma unroll
        for (int g = 0; g < 4; g++){
            float vl0 = 0.f, vr0 = 0.f, vl1 = 0.f, vr1 = 0.f;
            #pragma unroll
            for (int ni = 0; ni < 4; ni++){
                vl0 += acc[mi][ni][g] * alv[ni];
                vr0 += acc[mi][ni][g] * arv[ni];
            }
            #pragma unroll
            for (int ni = 4; ni < 8; ni++){
                vl1 += acc[mi][ni][g] * alv[ni];
                vr1 += acc[mi][ni][g] * arv[ni];
            }
            #pragma unroll
            for (int off = 1; off < 16; off <<= 1){
                vl0 += __shfl_xor(vl0, off); vr0 += __shfl_xor(vr0, off);
                vl1 += __shfl_xor(vl1, off); vr1 += __shfl_xor(vr1, off);
            }
            int row = m0 + wr * 64 + mi * 16 + (lane >> 4) * 4 + g;
            if (l15 == 0 && row < NN){
                elr_[(size_t)row * HH + hh0]     = vl0;
                err_[(size_t)row * HH + hh0]     = vr0;
                elr_[(size_t)row * HH + hh0 + 1] = vl1;
                err_[(size_t)row * HH + hh0 + 1] = vr1;
            }
        }
    }
}

// ------- GAT edge-softmax + aggregation: wave-per-node, 64-edge superbatches -------
__global__ __launch_bounds__(256) void aggregate_kernel(
        const int* __restrict__ row_ptr, const int* __restrict__ ssrc,
        const float* __restrict__ el, const float* __restrict__ er,
        const _Float16* __restrict__ Hh, const float* __restrict__ bias,
        _Float16* __restrict__ zh){
    int wave = threadIdx.x >> 6;
    int lane = threadIdx.x & 63;
    int n = blockIdx.x * 4 + wave;
    int r = blockIdx.y;
    if (n >= NN) return;
    int beg = row_ptr[r * (NN + 1) + n];
    int deg = row_ptr[r * (NN + 1) + n + 1] - beg;
    int h1 = lane & 7;      // weight layout: head
    int slot = lane >> 3;   // weight layout: edge slot
    int h2 = lane >> 3;     // accumulate layout: head owning channels lane*8..+7
    const int* sp = ssrc + (size_t)r * EE + beg;
    const float* elp = el + (size_t)r * NN * HH;

    float o[8];
    #pragma unroll
    for (int k = 0; k < 8; k++) o[k] = 0.f;

    if (deg > 0){
        float er1 = er[((size_t)r * NN + n) * HH + h1];
        float m = -INFINITY, den = 0.f;
        // ---- pass 1: (m, den) per head; 64-edge superbatch, 8 independent gathers ----
        for (int e0 = 0; e0 < deg; e0 += 64){
            int nb = min(64, deg - e0);
            int myv = (lane < nb) ? sp[e0 + lane] : 0;
            float x[8];
            #pragma unroll
            for (int sub = 0; sub < 8; sub++){
                if (sub * 8 < nb){
                    int j = sub * 8 + slot;
                    int s = __shfl(myv, j);
                    float xv = elp[(size_t)s * HH + h1] + er1;
                    xv = (xv > 0.f) ? xv : 0.2f * xv;
                    x[sub] = (j < nb) ? xv : -INFINITY;
                } else {
                    x[sub] = -INFINITY;
                }
            }
            float mb = x[0];
            #pragma unroll
            for (int sub = 1; sub < 8; sub++) mb = fmaxf(mb, x[sub]);
            float M = fmaxf(m, mb);
            float db = 0.f;
            #pragma unroll
            for (int sub = 0; sub < 8; sub++) db += __expf(fmaxf(x[sub] - M, -80.f));
            den = den * __expf(fmaxf(m - M, -80.f)) + db;
            m = M;
        }
        // butterfly across slot groups (each head replicated on 8 lanes)
        #pragma unroll
        for (int st = 8; st < 64; st <<= 1){
            float m2 = __shfl_xor(m, st);
            float d2 = __shfl_xor(den, st);
            float M = fmaxf(m, m2);
            den = den * __expf(fmaxf(m - M, -80.f)) + d2 * __expf(fmaxf(m2 - M, -80.f));
            m = M;
        }
        float inv = (den > 0.f) ? 1.f / den : 0.f;
        const _Float16* Hr = Hh + (size_t)r * NN * DD;
        // ---- pass 2: 64-edge superbatch; phase A weights, phase B streaming gathers ----
        for (int e0 = 0; e0 < deg; e0 += 64){
            int nb = min(64, deg - e0);
            int myv = (lane < nb) ? sp[e0 + lane] : 0;
            float wreg[8];
            #pragma unroll
            for (int sub = 0; sub < 8; sub++){
                if (sub * 8 < nb){
                    int j = sub * 8 + slot;
                    int s = __shfl(myv, j);
                    float xv = elp[(size_t)s * HH + h1] + er1;
                    xv = (xv > 0.f) ? xv : 0.2f * xv;
                    wreg[sub] = (j < nb) ? __expf(fmaxf(xv - m, -80.f)) * inv : 0.f;
                } else {
                    wreg[sub] = 0.f;
                }
            }
            #pragma unroll
            for (int sub = 0; sub < 8; sub++){
                if (sub * 8 >= nb) break;   // wave-uniform
                #pragma unroll
                for (int j2 = 0; j2 < 8; j2++){
                    int j = sub * 8 + j2;
                    if (j < nb){
                        float w = __shfl(wreg[sub], (j2 << 3) | h2);
                        int s = __shfl(myv, j);
                        half8 hv = *reinterpret_cast<const half8*>(Hr + (size_t)s * DD + lane * 8);
                        #pragma unroll
                        for (int k = 0; k < 8; k++) o[k] += w * (float)hv[k];
                    }
                }
            }
        }
    }
    const float* bp = bias + r * DD + lane * 8;
    union { uint4 u; _Float16 h[8]; } pk;
    #pragma unroll
    for (int k = 0; k < 8; k++){
        float v = o[k] + bp[k];
        v = fminf(fmaxf(v, 0.f), 6.f);
        pk.h[k] = (_Float16)v;
    }
    size_t zi = ((size_t)(r * NN + n)) * DD + lane * 8;
    *reinterpret_cast<uint4*>(zh + zi) = pk.u;
}

// ------- w-proj + fused beta partial sums: sums[r] += tanh(z@W1+b1)@W2 per row -------
__global__ __launch_bounds__(256) void wproj_kernel(
        const _Float16* __restrict__ Zh, const _Float16* __restrict__ W1t,
        const float* __restrict__ b1, const float* __restrict__ W2,
        float* __restrict__ sums){
    int lane = threadIdx.x & 63;
    int wave = threadIdx.x >> 6;
    int m0 = blockIdx.x * 64 + wave * 16;
    int arow = m0 + (lane & 15);
    if (arow >= RR * NN) arow = RR * NN - 1;
    int kg = (lane >> 4) * 8;
    f32x4 acc[4];
    #pragma unroll
    for (int f = 0; f < 4; f++) acc[f] = (f32x4){0.f, 0.f, 0.f, 0.f};
    const _Float16* ap = Zh + (size_t)arow * DD + kg;
    for (int k0 = 0; k0 < DD; k0 += 32){
        half8 af = *reinterpret_cast<const half8*>(ap + k0);
        #pragma unroll
        for (int f = 0; f < 4; f++){
            int col = f * 16 + (lane & 15);
            half8 bfr = *reinterpret_cast<const half8*>(W1t + (size_t)col * DD + k0 + kg);
            acc[f] = __builtin_amdgcn_mfma_f32_16x16x32_f16(af, bfr, acc[f], 0, 0, 0);
        }
    }
    float s[4] = {0.f, 0.f, 0.f, 0.f};
    #pragma unroll
    for (int f = 0; f < 4; f++){
        int col = f * 16 + (lane & 15);
        float bb = b1[col], ww = W2[col];
        #pragma unroll
        for (int g = 0; g < 4; g++) s[g] += tanhf(acc[f][g] + bb) * ww;
    }
    float tot = 0.f;
    #pragma unroll
    for (int g = 0; g < 4; g++){
        s[g] += __shfl_xor(s[g], 1);
        s[g] += __shfl_xor(s[g], 2);
        s[g] += __shfl_xor(s[g], 4);
        s[g] += __shfl_xor(s[g], 8);   // all 16 lanes of group now hold row total
        int row = m0 + (lane >> 4) * 4 + g;
        tot += (row < RR * NN) ? s[g] : 0.f;
    }
    // wave covers 16 consecutive rows (20000 % 16 == 0 -> single r per wave)
    tot = tot * 0.0625f;               // each group total replicated on 16 lanes
    tot += __shfl_xor(tot, 16);
    tot += __shfl_xor(tot, 32);
    if (lane == 0 && m0 < RR * NN){
        int rr = m0 / NN;
        atomicAdd(&sums[rr], tot);
    }
}

// ---------------- beta = softmax(sums / N) ----------------
__global__ void beta_small_kernel(const float* __restrict__ sums, float* __restrict__ beta){
    if (threadIdx.x == 0){
        float m0 = sums[0] / (float)NN, m1 = sums[1] / (float)NN, m2 = sums[2] / (float)NN;
        float mx = fmaxf(m0, fmaxf(m1, m2));
        float e0 = __expf(m0 - mx), e1 = __expf(m1 - mx), e2 = __expf(m2 - mx);
        float inv = 1.f / (e0 + e1 + e2);
        beta[0] = e0 * inv; beta[1] = e1 * inv; beta[2] = e2 * inv;
    }
}

// ---------------- out = sum_r beta_r * z_r ----------------
__global__ void final_kernel(const _Float16* __restrict__ zh, const float* __restrict__ beta,
                             float* __restrict__ out){
    int idx = blockIdx.x * blockDim.x + threadIdx.x;
    const int cnt = NN * DD / 4;
    if (idx >= cnt) return;
    float b0 = beta[0], b1 = beta[1], b2 = beta[2];
    const uint2* zp = reinterpret_cast<const uint2*>(zh);
    const size_t ps = (size_t)NN * DD / 4;
    uint2 a = zp[idx], b = zp[ps + idx], c = zp[2 * ps + idx];
    float2 a0 = up2(a.x), a1 = up2(a.y);
    float2 c0 = up2(b.x), c1 = up2(b.y);
    float2 e0 = up2(c.x), e1 = up2(c.y);
    float4 o;
    o.x = b0 * a0.x + b1 * c0.x + b2 * e0.x;
    o.y = b0 * a0.y + b1 * c0.y + b2 * e0.y;
    o.z = b0 * a1.x + b1 * c1.x + b2 * e1.x;
    o.w = b0 * a1.y + b1 * c1.y + b2 * e1.y;
    reinterpret_cast<float4*>(out)[idx] = o;
}

extern "C" void kernel_launch(void* const* d_in, const int* in_sizes, int n_in,
                              void* d_out, int out_size, void* d_ws, size_t ws_size,
                              hipStream_t stream){
    const float* feats = (const float*)d_in[0];
    const int*   src   = (const int*)d_in[1];
    const int*   dst   = (const int*)d_in[2];
    const float* W     = (const float*)d_in[3];
    const float* al    = (const float*)d_in[4];
    const float* ar    = (const float*)d_in[5];
    const float* bias  = (const float*)d_in[6];
    const float* W1    = (const float*)d_in[7];
    const float* b1    = (const float*)d_in[8];
    const float* W2    = (const float*)d_in[9];
    float* out = (float*)d_out;

    char* ws = (char*)d_ws;
    size_t off = 0;
    auto alloc = [&](size_t bytes) -> void* {
        void* p = (void*)(ws + off);
        off += (bytes + 255) & ~(size_t)255;
        return p;
    };
    _Float16* Wthi  = (_Float16*)alloc((size_t)RR * DD * FF * 2);
    _Float16* Wtlo  = (_Float16*)alloc((size_t)RR * DD * FF * 2);
    _Float16* W1t   = (_Float16*)alloc((size_t)OO * DD * 2);
    _Float16* Hh    = (_Float16*)alloc((size_t)RR * NN * DD * 2);
    float*    el    = (float*)alloc((size_t)RR * NN * HH * 4);
    float*    er    = (float*)alloc((size_t)RR * NN * HH * 4);
    _Float16* zh    = (_Float16*)alloc((size_t)RR * NN * DD * 2);
    int*      counts  = (int*)alloc((size_t)RR * NN * 4);      // doubles as cursor
    int*      row_ptr = (int*)alloc((size_t)RR * (NN + 1) * 4);
    int*      ssrc    = (int*)alloc((size_t)RR * EE * 4);
    float*    sums    = (float*)alloc(256);
    float*    beta    = (float*)alloc(256);

    hipMemsetAsync(counts, 0, (size_t)RR * NN * 4, stream);
    hipMemsetAsync(sums, 0, RR * 4, stream);
    prep_weights_kernel<<<(RR * DD * FF + OO * DD + 255) / 256, 256, 0, stream>>>(
        W, W1, Wthi, Wtlo, W1t);
    hist_kernel<<<(RR * EE + 255) / 256, 256, 0, stream>>>(dst, counts);
    scan_kernel<<<RR, 1024, 0, stream>>>(counts, row_ptr);
    scatter_kernel<<<(RR * EE + 255) / 256, 256, 0, stream>>>(src, dst, counts, ssrc);
    gemm_h_kernel<<<dim3((NN + BM - 1) / BM, DD / BN, RR), 256, 0, stream>>>(
        feats, Wthi, Wtlo, al, ar, Hh, el, er);
    aggregate_kernel<<<dim3((NN + 3) / 4, RR), 256, 0, stream>>>(
        row_ptr, ssrc, el, er, Hh, bias, zh);
    wproj_kernel<<<(RR * NN + 63) / 64, 256, 0, stream>>>(zh, W1t, b1, W2, sums);
    beta_small_kernel<<<1, 64, 0, stream>>>(sums, beta);
    final_kernel<<<(NN * DD / 4 + 255) / 256, 256, 0, stream>>>(zh, beta, out);
}

// Round 7
// 554.417 us; speedup vs baseline: 1.1136x; 1.1136x over previous
//
#include <hip/hip_runtime.h>
#include <hip/hip_bf16.h>

#define RR 3
#define NN 20000
#define EE 320000
#define FF 256
#define HH 8
#define OO 64
#define DD 512

typedef _Float16 half8 __attribute__((ext_vector_type(8)));
typedef float f32x4 __attribute__((ext_vector_type(4)));

__device__ __forceinline__ float2 up2(unsigned int u){
    union { unsigned int u; _Float16 h[2]; } t; t.u = u;
    return make_float2((float)t.h[0], (float)t.h[1]);
}

__device__ __forceinline__ void gl_lds16(const void* g, void* l){
    __builtin_amdgcn_global_load_lds(
        (const __attribute__((address_space(1))) unsigned int*)g,
        (__attribute__((address_space(3))) unsigned int*)l, 16, 0, 0);
}

// ---- transpose+split W -> fp16 hi/lo, transpose W1 -> W1t[j][i] fp16, zero counts ----
__global__ void prep_weights_kernel(const float* __restrict__ W, const float* __restrict__ W1,
                                    _Float16* __restrict__ Wthi, _Float16* __restrict__ Wtlo,
                                    _Float16* __restrict__ W1t, int* __restrict__ counts){
    int idx = blockIdx.x * blockDim.x + threadIdx.x;
    const int c1 = RR * DD * FF;
    if (idx < RR * NN) counts[idx] = 0;
    if (idx < c1){
        int r = idx / (DD * FF);
        int rem = idx % (DD * FF);
        int d = rem / FF;
        int k = rem % FF;
        float v = W[(size_t)r * FF * DD + (size_t)k * DD + d];
        _Float16 h = (_Float16)v;
        Wthi[idx] = h;
        Wtlo[idx] = (_Float16)(v - (float)h);
    } else if (idx < c1 + OO * DD){
        int idx2 = idx - c1;
        int j = idx2 / DD;
        int i = idx2 % DD;
        W1t[idx2] = (_Float16)W1[(size_t)i * OO + j];
    }
}

// ---------------- CSR build ----------------
__global__ void hist_kernel(const int* __restrict__ dst, int* __restrict__ counts){
    int idx = blockIdx.x * blockDim.x + threadIdx.x;
    if (idx >= RR * EE) return;
    int r = idx / EE;
    atomicAdd(&counts[r * NN + dst[idx]], 1);
}

// 20 contiguous elements per thread; one block-scan round; also zeroes sums
__global__ __launch_bounds__(1024) void scan_kernel(int* __restrict__ counts,  // also cursor (aliased)
                            int* __restrict__ row_ptr, float* __restrict__ sums){
    int r = blockIdx.x;
    int tid = threadIdx.x, lane = tid & 63, wid = tid >> 6;
    if (r == 0 && tid < RR) sums[tid] = 0.f;
    __shared__ int wsum[16];
    const int PER = 20;
    int base = tid * PER;
    int* cr = counts + r * NN;
    int vals[PER];
    int sum = 0;
    #pragma unroll
    for (int i = 0; i < PER; i++){
        int idx = base + i;
        int v = (idx < NN) ? cr[idx] : 0;
        vals[i] = v;
        sum += v;
    }
    int inc = sum;
    #pragma unroll
    for (int off = 1; off < 64; off <<= 1){
        int t = __shfl_up(inc, off, 64);
        if (lane >= off) inc += t;
    }
    if (lane == 63) wsum[wid] = inc;
    __syncthreads();
    if (wid == 0 && lane < 16){
        int s = wsum[lane];
        int si = s;
        #pragma unroll
        for (int off = 1; off < 16; off <<= 1){
            int t = __shfl_up(si, off, 16);
            if (lane >= off) si += t;
        }
        wsum[lane] = si - s;   // exclusive wave offset
    }
    __syncthreads();
    int run = (inc - sum) + wsum[wid];
    if (tid == 0) row_ptr[r * (NN + 1)] = 0;
    #pragma unroll
    for (int i = 0; i < PER; i++){
        int idx = base + i;
        if (idx < NN){
            cr[idx] = run;                       // cursor = exclusive start
            run += vals[i];
            row_ptr[r * (NN + 1) + idx + 1] = run;
        }
    }
}

__global__ void scatter_kernel(const int* __restrict__ src, const int* __restrict__ dst,
                               int* __restrict__ cursor, int* __restrict__ ssrc){
    int idx = blockIdx.x * blockDim.x + threadIdx.x;
    if (idx >= RR * EE) return;
    int r = idx / EE;
    int pos = atomicAdd(&cursor[r * NN + dst[idx]], 1);
    ssrc[(size_t)r * EE + pos] = src[idx];
}

// ------- h = feats @ W (128x256 LDS-tiled MFMA, 2-pass B-split fp16) + fused el/er -------
#define BM 128
#define BN 256
#define BK 32
#define APAD 36   // fp32 row stride in LDS (32 + 4 pad)

__global__ __launch_bounds__(256) void gemm_h_kernel(
        const float* __restrict__ feats,
        const _Float16* __restrict__ Wthi, const _Float16* __restrict__ Wtlo,
        const float* __restrict__ al, const float* __restrict__ ar,
        _Float16* __restrict__ Hout, float* __restrict__ elo, float* __restrict__ ero){
    __shared__ float    sA[BM * APAD];
    __shared__ _Float16 sBh[BN * BK];
    __shared__ _Float16 sBl[BN * BK];
    int r = blockIdx.z;
    int m0 = blockIdx.x * BM;
    int n0 = blockIdx.y * BN;
    const float* A = feats + (size_t)r * NN * FF;
    const _Float16* Bh = Wthi + (size_t)r * DD * FF;
    const _Float16* Bl = Wtlo + (size_t)r * DD * FF;
    int t = threadIdx.x;
    int lane = t & 63;
    int wave = t >> 6;
    int wr = wave >> 1, wc = wave & 1;   // wave tile: rows wr*64, cols wc*128
    int l15 = lane & 15;
    int kg = (lane >> 4) * 8;

    f32x4 acc[4][8];
    #pragma unroll
    for (int mi = 0; mi < 4; mi++)
        #pragma unroll
        for (int ni = 0; ni < 8; ni++)
            acc[mi][ni] = (f32x4){0.f, 0.f, 0.f, 0.f};

    int arr[4];
    #pragma unroll
    for (int i = 0; i < 4; i++){
        int row = (t + i * 256) >> 3;
        int gr = m0 + row;
        arr[i] = (gr < NN) ? gr : (NN - 1);
    }

    for (int k0 = 0; k0 < FF; k0 += BK){
        __syncthreads();
        #pragma unroll
        for (int i = 0; i < 4; i++){
            int c = t + i * 256;
            int row = c >> 3, kc = c & 7;
            float4 v = *reinterpret_cast<const float4*>(A + (size_t)arr[i] * FF + k0 + kc * 4);
            *reinterpret_cast<float4*>(&sA[row * APAD + kc * 4]) = v;
        }
        #pragma unroll
        for (int i = 0; i < 4; i++){
            int c = t + i * 256;
            int row = c >> 2, kc = c & 3;
            size_t goff = (size_t)(n0 + row) * FF + k0 + kc * 8;
            gl_lds16(Bh + goff, &sBh[c * 8]);
            gl_lds16(Bl + goff, &sBl[c * 8]);
        }
        __syncthreads();

        half8 af[4];
        #pragma unroll
        for (int mi = 0; mi < 4; mi++){
            const float* ap = &sA[(wr * 64 + mi * 16 + l15) * APAD + kg];
            float4 x = *reinterpret_cast<const float4*>(ap);
            float4 y = *reinterpret_cast<const float4*>(ap + 4);
            af[mi][0] = (_Float16)x.x; af[mi][1] = (_Float16)x.y;
            af[mi][2] = (_Float16)x.z; af[mi][3] = (_Float16)x.w;
            af[mi][4] = (_Float16)y.x; af[mi][5] = (_Float16)y.y;
            af[mi][6] = (_Float16)y.z; af[mi][7] = (_Float16)y.w;
        }
        #pragma unroll
        for (int ni = 0; ni < 8; ni++){
            int cb = (wc * 128 + ni * 16 + l15) * BK + kg;
            half8 bh = *reinterpret_cast<const half8*>(&sBh[cb]);
            half8 bl = *reinterpret_cast<const half8*>(&sBl[cb]);
            #pragma unroll
            for (int mi = 0; mi < 4; mi++){
                acc[mi][ni] = __builtin_amdgcn_mfma_f32_16x16x32_f16(af[mi], bh, acc[mi][ni], 0, 0, 0);
                acc[mi][ni] = __builtin_amdgcn_mfma_f32_16x16x32_f16(af[mi], bl, acc[mi][ni], 0, 0, 0);
            }
        }
    }

    _Float16* Hr = Hout + (size_t)r * NN * DD;
    #pragma unroll
    for (int mi = 0; mi < 4; mi++){
        #pragma unroll
        for (int g = 0; g < 4; g++){
            int row = m0 + wr * 64 + mi * 16 + (lane >> 4) * 4 + g;
            if (row < NN){
                #pragma unroll
                for (int ni = 0; ni < 8; ni++){
                    int col = n0 + wc * 128 + ni * 16 + l15;
                    Hr[(size_t)row * DD + col] = (_Float16)acc[mi][ni][g];
                }
            }
        }
    }

    // ---- fused el/er: this wave's 128 cols span heads hh0, hh0+1 ----
    int hh0 = blockIdx.y * 4 + wc * 2;
    const float* alp = al + r * DD + hh0 * OO;
    const float* arp = ar + r * DD + hh0 * OO;
    float alv[8], arv[8];
    #pragma unroll
    for (int ni = 0; ni < 8; ni++){
        int off2 = (ni >> 2) * OO + (ni & 3) * 16 + l15;
        alv[ni] = alp[off2];
        arv[ni] = arp[off2];
    }
    float* elr_ = elo + (size_t)r * NN * HH;
    float* err_ = ero + (size_t)r * NN * HH;
    #pragma unroll
    for (int mi = 0; mi < 4; mi++){
        #pragma unroll
        for (int g = 0; g < 4; g++){
            float vl0 = 0.f, vr0 = 0.f, vl1 = 0.f, vr1 = 0.f;
            #pragma unroll
            for (int ni = 0; ni < 4; ni++){
                vl0 += acc[mi][ni][g] * alv[ni];
                vr0 += acc[mi][ni][g] * arv[ni];
            }
            #pragma unroll
            for (int ni = 4; ni < 8; ni++){
                vl1 += acc[mi][ni][g] * alv[ni];
                vr1 += acc[mi][ni][g] * arv[ni];
            }
            #pragma unroll
            for (int off = 1; off < 16; off <<= 1){
                vl0 += __shfl_xor(vl0, off); vr0 += __shfl_xor(vr0, off);
                vl1 += __shfl_xor(vl1, off); vr1 += __shfl_xor(vr1, off);
            }
            int row = m0 + wr * 64 + mi * 16 + (lane >> 4) * 4 + g;
            if (l15 == 0 && row < NN){
                elr_[(size_t)row * HH + hh0]     = vl0;
                err_[(size_t)row * HH + hh0]     = vr0;
                elr_[(size_t)row * HH + hh0 + 1] = vl1;
                err_[(size_t)row * HH + hh0 + 1] = vr1;
            }
        }
    }
}

// ------- GAT edge-softmax + aggregation: wave-per-node (r4 structure, best measured) -------
__global__ __launch_bounds__(256) void aggregate_kernel(
        const int* __restrict__ row_ptr, const int* __restrict__ ssrc,
        const float* __restrict__ el, const float* __restrict__ er,
        const _Float16* __restrict__ Hh, const float* __restrict__ bias,
        _Float16* __restrict__ zh){
    int wave = threadIdx.x >> 6;
    int lane = threadIdx.x & 63;
    int n = blockIdx.x * 4 + wave;
    int r = blockIdx.y;
    if (n >= NN) return;
    int beg = row_ptr[r * (NN + 1) + n];
    int deg = row_ptr[r * (NN + 1) + n + 1] - beg;
    int h1 = lane & 7;      // pass-1: head
    int slot = lane >> 3;   // pass-1: edge slot
    int h2 = lane >> 3;     // pass-2: head owning channels lane*8..lane*8+7
    const int* sp = ssrc + (size_t)r * EE + beg;
    const float* elp = el + (size_t)r * NN * HH;

    float o[8];
    #pragma unroll
    for (int k = 0; k < 8; k++) o[k] = 0.f;

    if (deg > 0){
        float er1 = er[((size_t)r * NN + n) * HH + h1];
        float m = -INFINITY, den = 0.f;
        // ---- pass 1: per-head online (m, den), 8 edges x 8 heads per iter ----
        for (int e0 = 0; e0 < deg; e0 += 8){
            int e = e0 + slot;
            if (e < deg){
                int s = sp[e];
                float x = elp[(size_t)s * HH + h1] + er1;
                x = (x > 0.f) ? x : 0.2f * x;
                float mn = fmaxf(m, x);
                den = den * __expf(fmaxf(m - mn, -80.f)) + __expf(fmaxf(x - mn, -80.f));
                m = mn;
            }
        }
        #pragma unroll
        for (int st = 8; st < 64; st <<= 1){
            float m2 = __shfl_xor(m, st);
            float d2 = __shfl_xor(den, st);
            float M = fmaxf(m, m2);
            den = den * __expf(fmaxf(m - M, -80.f)) + d2 * __expf(fmaxf(m2 - M, -80.f));
            m = M;
        }
        float m_p = __shfl(m, h2);
        float d_p = __shfl(den, h2);
        float inv = (d_p > 0.f) ? 1.f / d_p : 0.f;
        float er2 = er[((size_t)r * NN + n) * HH + h2];
        const _Float16* Hr = Hh + (size_t)r * NN * DD;
        // ---- pass 2: weight + gather-accumulate, 8 channels/lane ----
        for (int e0 = 0; e0 < deg; e0 += 8){
            int nb = min(8, deg - e0);
            int myv = (lane < nb) ? sp[e0 + lane] : 0;
            for (int j = 0; j < nb; j++){
                int s = __shfl(myv, j);
                float x = elp[(size_t)s * HH + h2] + er2;
                x = (x > 0.f) ? x : 0.2f * x;
                float w = __expf(fmaxf(x - m_p, -80.f)) * inv;
                half8 hv = *reinterpret_cast<const half8*>(Hr + (size_t)s * DD + lane * 8);
                #pragma unroll
                for (int k = 0; k < 8; k++) o[k] += w * (float)hv[k];
            }
        }
    }
    const float* bp = bias + r * DD + lane * 8;
    union { uint4 u; _Float16 h[8]; } pk;
    #pragma unroll
    for (int k = 0; k < 8; k++){
        float v = o[k] + bp[k];
        v = fminf(fmaxf(v, 0.f), 6.f);
        pk.h[k] = (_Float16)v;
    }
    size_t zi = ((size_t)(r * NN + n)) * DD + lane * 8;
    *reinterpret_cast<uint4*>(zh + zi) = pk.u;
}

// ------- w-proj (W1t staged in LDS, two k-halves) + fused beta partial sums -------
#define WKP 264   // padded fp16 stride per col per k-half (256 + 8)
__global__ __launch_bounds__(256) void wproj_kernel(
        const _Float16* __restrict__ Zh, const _Float16* __restrict__ W1t,
        const float* __restrict__ b1, const float* __restrict__ W2,
        float* __restrict__ sums){
    __shared__ _Float16 sW[64 * WKP];
    int t = threadIdx.x;
    int lane = t & 63;
    int wave = t >> 6;
    int l15 = lane & 15;
    int m0 = blockIdx.x * 64 + wave * 16;
    int arow = m0 + l15;
    if (arow >= RR * NN) arow = RR * NN - 1;
    int kg = (lane >> 4) * 8;
    f32x4 acc[4];
    #pragma unroll
    for (int f = 0; f < 4; f++) acc[f] = (f32x4){0.f, 0.f, 0.f, 0.f};
    const _Float16* ap = Zh + (size_t)arow * DD + kg;
    int scol = t >> 2, sseg = t & 3;   // staging map: 64 fp16 per thread per half
    #pragma unroll
    for (int half = 0; half < 2; half++){
        // stage k-half: cols 0..63, k in [half*256, half*256+256)
        {
            const _Float16* gp = W1t + (size_t)scol * DD + half * 256 + sseg * 64;
            _Float16* lp = &sW[scol * WKP + sseg * 64];
            __syncthreads();   // prior compute done reading LDS
            #pragma unroll
            for (int i = 0; i < 8; i++){
                *reinterpret_cast<uint4*>(lp + i * 8) =
                    *reinterpret_cast<const uint4*>(gp + i * 8);
            }
            __syncthreads();
        }
        #pragma unroll
        for (int kk = 0; kk < 256; kk += 32){
            int k0 = half * 256 + kk;
            half8 af = *reinterpret_cast<const half8*>(ap + k0);
            #pragma unroll
            for (int f = 0; f < 4; f++){
                int col = f * 16 + l15;
                half8 bfr = *reinterpret_cast<const half8*>(&sW[col * WKP + kk + kg]);
                acc[f] = __builtin_amdgcn_mfma_f32_16x16x32_f16(af, bfr, acc[f], 0, 0, 0);
            }
        }
    }
    float s[4] = {0.f, 0.f, 0.f, 0.f};
    #pragma unroll
    for (int f = 0; f < 4; f++){
        int col = f * 16 + l15;
        float bb = b1[col], ww = W2[col];
        #pragma unroll
        for (int g = 0; g < 4; g++) s[g] += tanhf(acc[f][g] + bb) * ww;
    }
    float tot = 0.f;
    #pragma unroll
    for (int g = 0; g < 4; g++){
        s[g] += __shfl_xor(s[g], 1);
        s[g] += __shfl_xor(s[g], 2);
        s[g] += __shfl_xor(s[g], 4);
        s[g] += __shfl_xor(s[g], 8);   // all 16 lanes of group hold row total
        int row = m0 + (lane >> 4) * 4 + g;
        tot += (row < RR * NN) ? s[g] : 0.f;
    }
    // wave covers 16 consecutive rows (20000 % 16 == 0 -> single r per wave)
    tot = tot * 0.0625f;
    tot += __shfl_xor(tot, 16);
    tot += __shfl_xor(tot, 32);
    if (lane == 0 && m0 < RR * NN){
        int rr = m0 / NN;
        atomicAdd(&sums[rr], tot);
    }
}

// ---------------- out = sum_r beta_r * z_r  (beta softmax computed inline) ----------------
__global__ void final_kernel(const _Float16* __restrict__ zh, const float* __restrict__ sums,
                             float* __restrict__ out){
    int idx = blockIdx.x * blockDim.x + threadIdx.x;
    const int cnt = NN * DD / 4;
    if (idx >= cnt) return;
    float m0 = sums[0] * (1.f / NN), m1 = sums[1] * (1.f / NN), m2 = sums[2] * (1.f / NN);
    float mx = fmaxf(m0, fmaxf(m1, m2));
    float e0 = __expf(m0 - mx), e1 = __expf(m1 - mx), e2 = __expf(m2 - mx);
    float inv = 1.f / (e0 + e1 + e2);
    float b0 = e0 * inv, b1 = e1 * inv, b2 = e2 * inv;
    const uint2* zp = reinterpret_cast<const uint2*>(zh);
    const size_t ps = (size_t)NN * DD / 4;
    uint2 a = zp[idx], b = zp[ps + idx], c = zp[2 * ps + idx];
    float2 a0 = up2(a.x), a1 = up2(a.y);
    float2 c0 = up2(b.x), c1 = up2(b.y);
    float2 e0f = up2(c.x), e1f = up2(c.y);
    float4 o;
    o.x = b0 * a0.x + b1 * c0.x + b2 * e0f.x;
    o.y = b0 * a0.y + b1 * c0.y + b2 * e0f.y;
    o.z = b0 * a1.x + b1 * c1.x + b2 * e1f.x;
    o.w = b0 * a1.y + b1 * c1.y + b2 * e1f.y;
    reinterpret_cast<float4*>(out)[idx] = o;
}

extern "C" void kernel_launch(void* const* d_in, const int* in_sizes, int n_in,
                              void* d_out, int out_size, void* d_ws, size_t ws_size,
                              hipStream_t stream){
    const float* feats = (const float*)d_in[0];
    const int*   src   = (const int*)d_in[1];
    const int*   dst   = (const int*)d_in[2];
    const float* W     = (const float*)d_in[3];
    const float* al    = (const float*)d_in[4];
    const float* ar    = (const float*)d_in[5];
    const float* bias  = (const float*)d_in[6];
    const float* W1    = (const float*)d_in[7];
    const float* b1    = (const float*)d_in[8];
    const float* W2    = (const float*)d_in[9];
    float* out = (float*)d_out;

    char* ws = (char*)d_ws;
    size_t off = 0;
    auto alloc = [&](size_t bytes) -> void* {
        void* p = (void*)(ws + off);
        off += (bytes + 255) & ~(size_t)255;
        return p;
    };
    _Float16* Wthi  = (_Float16*)alloc((size_t)RR * DD * FF * 2);
    _Float16* Wtlo  = (_Float16*)alloc((size_t)RR * DD * FF * 2);
    _Float16* W1t   = (_Float16*)alloc((size_t)OO * DD * 2);
    _Float16* Hh    = (_Float16*)alloc((size_t)RR * NN * DD * 2);
    float*    el    = (float*)alloc((size_t)RR * NN * HH * 4);
    float*    er    = (float*)alloc((size_t)RR * NN * HH * 4);
    _Float16* zh    = (_Float16*)alloc((size_t)RR * NN * DD * 2);
    int*      counts  = (int*)alloc((size_t)RR * NN * 4);      // doubles as cursor
    int*      row_ptr = (int*)alloc((size_t)RR * (NN + 1) * 4);
    int*      ssrc    = (int*)alloc((size_t)RR * EE * 4);
    float*    sums    = (float*)alloc(256);

    prep_weights_kernel<<<(RR * DD * FF + OO * DD + 255) / 256, 256, 0, stream>>>(
        W, W1, Wthi, Wtlo, W1t, counts);
    hist_kernel<<<(RR * EE + 255) / 256, 256, 0, stream>>>(dst, counts);
    scan_kernel<<<RR, 1024, 0, stream>>>(counts, row_ptr, sums);
    scatter_kernel<<<(RR * EE + 255) / 256, 256, 0, stream>>>(src, dst, counts, ssrc);
    gemm_h_kernel<<<dim3((NN + BM - 1) / BM, DD / BN, RR), 256, 0, stream>>>(
        feats, Wthi, Wtlo, al, ar, Hh, el, er);
    aggregate_kernel<<<dim3((NN + 3) / 4, RR), 256, 0, stream>>>(
        row_ptr, ssrc, el, er, Hh, bias, zh);
    wproj_kernel<<<(RR * NN + 63) / 64, 256, 0, stream>>>(zh, W1t, b1, W2, sums);
    final_kernel<<<(NN * DD / 4 + 255) / 256, 256, 0, stream>>>(zh, sums, out);
}

// Round 8
// 523.706 us; speedup vs baseline: 1.1789x; 1.0586x over previous
//
#include <hip/hip_runtime.h>
#include <hip/hip_bf16.h>

#define RR 3
#define NN 20000
#define EE 320000
#define FF 256
#define HH 8
#define OO 64
#define DD 512

typedef _Float16 half8 __attribute__((ext_vector_type(8)));
typedef float f32x4 __attribute__((ext_vector_type(4)));

__device__ __forceinline__ float2 up2(unsigned int u){
    union { unsigned int u; _Float16 h[2]; } t; t.u = u;
    return make_float2((float)t.h[0], (float)t.h[1]);
}

__device__ __forceinline__ void gl_lds16(const void* g, void* l){
    __builtin_amdgcn_global_load_lds(
        (const __attribute__((address_space(1))) unsigned int*)g,
        (__attribute__((address_space(3))) unsigned int*)l, 16, 0, 0);
}

// ---- W[r][k][d] fp32 -> Wt[r][d][k] fp16, LDS-tiled transpose (coalesced both sides) ----
__global__ __launch_bounds__(256) void transpose_W_kernel(const float* __restrict__ W,
                                                          _Float16* __restrict__ Wt){
    int bid = blockIdx.x;           // r*64 + kt*8 + dt
    int r = bid >> 6;
    int kt = (bid >> 3) & 7, dt = bid & 7;
    int k0 = kt * 32, d0 = dt * 64;
    __shared__ float sT[64][33];
    int t = threadIdx.x;
    const float* Wr = W + (size_t)r * FF * DD;
    #pragma unroll
    for (int it = 0; it < 2; it++){
        int kk = (t >> 4) + it * 16;      // 0..31
        int dd = (t & 15) * 4;
        float4 v = *reinterpret_cast<const float4*>(Wr + (size_t)(k0 + kk) * DD + d0 + dd);
        sT[dd + 0][kk] = v.x; sT[dd + 1][kk] = v.y;
        sT[dd + 2][kk] = v.z; sT[dd + 3][kk] = v.w;
    }
    __syncthreads();
    int dd = t >> 2, seg = (t & 3) * 8;
    union { uint4 u; _Float16 h[8]; } pk;
    #pragma unroll
    for (int i = 0; i < 8; i++) pk.h[i] = (_Float16)sT[dd][seg + i];
    *reinterpret_cast<uint4*>(Wt + (size_t)r * DD * FF + (size_t)(d0 + dd) * FF + k0 + seg) = pk.u;
}

// ---- small prep: W1 -> W1t[j][i] fp16, zero counts ----
__global__ void prep_small_kernel(const float* __restrict__ W1, _Float16* __restrict__ W1t,
                                  int* __restrict__ counts){
    int idx = blockIdx.x * blockDim.x + threadIdx.x;
    if (idx < RR * NN) counts[idx] = 0;
    if (idx < OO * DD){
        int j = idx / DD;
        int i = idx % DD;
        W1t[idx] = (_Float16)W1[(size_t)i * OO + j];
    }
}

// ---------------- CSR build ----------------
__global__ void hist_kernel(const int* __restrict__ dst, int* __restrict__ counts){
    int idx = blockIdx.x * blockDim.x + threadIdx.x;
    if (idx >= RR * EE) return;
    int r = idx / EE;
    atomicAdd(&counts[r * NN + dst[idx]], 1);
}

// 20 contiguous elements per thread; one block-scan round; also zeroes sums
__global__ __launch_bounds__(1024) void scan_kernel(int* __restrict__ counts,  // also cursor (aliased)
                            int* __restrict__ row_ptr, float* __restrict__ sums){
    int r = blockIdx.x;
    int tid = threadIdx.x, lane = tid & 63, wid = tid >> 6;
    if (r == 0 && tid < RR) sums[tid] = 0.f;
    __shared__ int wsum[16];
    const int PER = 20;
    int base = tid * PER;
    int* cr = counts + r * NN;
    int vals[PER];
    int sum = 0;
    #pragma unroll
    for (int i = 0; i < PER; i++){
        int idx = base + i;
        int v = (idx < NN) ? cr[idx] : 0;
        vals[i] = v;
        sum += v;
    }
    int inc = sum;
    #pragma unroll
    for (int off = 1; off < 64; off <<= 1){
        int t = __shfl_up(inc, off, 64);
        if (lane >= off) inc += t;
    }
    if (lane == 63) wsum[wid] = inc;
    __syncthreads();
    if (wid == 0 && lane < 16){
        int s = wsum[lane];
        int si = s;
        #pragma unroll
        for (int off = 1; off < 16; off <<= 1){
            int t = __shfl_up(si, off, 16);
            if (lane >= off) si += t;
        }
        wsum[lane] = si - s;   // exclusive wave offset
    }
    __syncthreads();
    int run = (inc - sum) + wsum[wid];
    if (tid == 0) row_ptr[r * (NN + 1)] = 0;
    #pragma unroll
    for (int i = 0; i < PER; i++){
        int idx = base + i;
        if (idx < NN){
            cr[idx] = run;                       // cursor = exclusive start
            run += vals[i];
            row_ptr[r * (NN + 1) + idx + 1] = run;
        }
    }
}

__global__ void scatter_kernel(const int* __restrict__ src, const int* __restrict__ dst,
                               int* __restrict__ cursor, int* __restrict__ ssrc){
    int idx = blockIdx.x * blockDim.x + threadIdx.x;
    if (idx >= RR * EE) return;
    int r = idx / EE;
    int pos = atomicAdd(&cursor[r * NN + dst[idx]], 1);
    ssrc[(size_t)r * EE + pos] = src[idx];
}

// ------- h = feats @ W (128x256 LDS-tiled MFMA, single-pass fp16 B) + fused el/er -------
#define BM 128
#define BN 256
#define BK 32
#define APAD 36   // fp32 row stride in LDS (32 + 4 pad)

__global__ __launch_bounds__(256) void gemm_h_kernel(
        const float* __restrict__ feats,
        const _Float16* __restrict__ Wthi,
        const float* __restrict__ al, const float* __restrict__ ar,
        _Float16* __restrict__ Hout, float* __restrict__ elo, float* __restrict__ ero){
    __shared__ float    sA[BM * APAD];
    __shared__ _Float16 sBh[BN * BK];
    int r = blockIdx.z;
    int m0 = blockIdx.x * BM;
    int n0 = blockIdx.y * BN;
    const float* A = feats + (size_t)r * NN * FF;
    const _Float16* Bh = Wthi + (size_t)r * DD * FF;
    int t = threadIdx.x;
    int lane = t & 63;
    int wave = t >> 6;
    int wr = wave >> 1, wc = wave & 1;   // wave tile: rows wr*64, cols wc*128
    int l15 = lane & 15;
    int kg = (lane >> 4) * 8;

    f32x4 acc[4][8];
    #pragma unroll
    for (int mi = 0; mi < 4; mi++)
        #pragma unroll
        for (int ni = 0; ni < 8; ni++)
            acc[mi][ni] = (f32x4){0.f, 0.f, 0.f, 0.f};

    int arr[4];
    #pragma unroll
    for (int i = 0; i < 4; i++){
        int row = (t + i * 256) >> 3;
        int gr = m0 + row;
        arr[i] = (gr < NN) ? gr : (NN - 1);
    }

    for (int k0 = 0; k0 < FF; k0 += BK){
        __syncthreads();
        #pragma unroll
        for (int i = 0; i < 4; i++){
            int c = t + i * 256;
            int row = c >> 3, kc = c & 7;
            float4 v = *reinterpret_cast<const float4*>(A + (size_t)arr[i] * FF + k0 + kc * 4);
            *reinterpret_cast<float4*>(&sA[row * APAD + kc * 4]) = v;
        }
        #pragma unroll
        for (int i = 0; i < 4; i++){
            int c = t + i * 256;
            int row = c >> 2, kc = c & 3;
            size_t goff = (size_t)(n0 + row) * FF + k0 + kc * 8;
            gl_lds16(Bh + goff, &sBh[c * 8]);
        }
        __syncthreads();

        half8 af[4];
        #pragma unroll
        for (int mi = 0; mi < 4; mi++){
            const float* ap = &sA[(wr * 64 + mi * 16 + l15) * APAD + kg];
            float4 x = *reinterpret_cast<const float4*>(ap);
            float4 y = *reinterpret_cast<const float4*>(ap + 4);
            af[mi][0] = (_Float16)x.x; af[mi][1] = (_Float16)x.y;
            af[mi][2] = (_Float16)x.z; af[mi][3] = (_Float16)x.w;
            af[mi][4] = (_Float16)y.x; af[mi][5] = (_Float16)y.y;
            af[mi][6] = (_Float16)y.z; af[mi][7] = (_Float16)y.w;
        }
        #pragma unroll
        for (int ni = 0; ni < 8; ni++){
            int cb = (wc * 128 + ni * 16 + l15) * BK + kg;
            half8 bh = *reinterpret_cast<const half8*>(&sBh[cb]);
            #pragma unroll
            for (int mi = 0; mi < 4; mi++){
                acc[mi][ni] = __builtin_amdgcn_mfma_f32_16x16x32_f16(af[mi], bh, acc[mi][ni], 0, 0, 0);
            }
        }
    }

    _Float16* Hr = Hout + (size_t)r * NN * DD;
    #pragma unroll
    for (int mi = 0; mi < 4; mi++){
        #pragma unroll
        for (int g = 0; g < 4; g++){
            int row = m0 + wr * 64 + mi * 16 + (lane >> 4) * 4 + g;
            if (row < NN){
                #pragma unroll
                for (int ni = 0; ni < 8; ni++){
                    int col = n0 + wc * 128 + ni * 16 + l15;
                    Hr[(size_t)row * DD + col] = (_Float16)acc[mi][ni][g];
                }
            }
        }
    }

    // ---- fused el/er: this wave's 128 cols span heads hh0, hh0+1 ----
    int hh0 = blockIdx.y * 4 + wc * 2;
    const float* alp = al + r * DD + hh0 * OO;
    const float* arp = ar + r * DD + hh0 * OO;
    float alv[8], arv[8];
    #pragma unroll
    for (int ni = 0; ni < 8; ni++){
        int off2 = (ni >> 2) * OO + (ni & 3) * 16 + l15;
        alv[ni] = alp[off2];
        arv[ni] = arp[off2];
    }
    float* elr_ = elo + (size_t)r * NN * HH;
    float* err_ = ero + (size_t)r * NN * HH;
    #pragma unroll
    for (int mi = 0; mi < 4; mi++){
        #pragma unroll
        for (int g = 0; g < 4; g++){
            float vl0 = 0.f, vr0 = 0.f, vl1 = 0.f, vr1 = 0.f;
            #pragma unroll
            for (int ni = 0; ni < 4; ni++){
                vl0 += acc[mi][ni][g] * alv[ni];
                vr0 += acc[mi][ni][g] * arv[ni];
            }
            #pragma unroll
            for (int ni = 4; ni < 8; ni++){
                vl1 += acc[mi][ni][g] * alv[ni];
                vr1 += acc[mi][ni][g] * arv[ni];
            }
            #pragma unroll
            for (int off = 1; off < 16; off <<= 1){
                vl0 += __shfl_xor(vl0, off); vr0 += __shfl_xor(vr0, off);
                vl1 += __shfl_xor(vl1, off); vr1 += __shfl_xor(vr1, off);
            }
            int row = m0 + wr * 64 + mi * 16 + (lane >> 4) * 4 + g;
            if (l15 == 0 && row < NN){
                elr_[(size_t)row * HH + hh0]     = vl0;
                err_[(size_t)row * HH + hh0]     = vr0;
                elr_[(size_t)row * HH + hh0 + 1] = vl1;
                err_[(size_t)row * HH + hh0 + 1] = vr1;
            }
        }
    }
}

// ------- GAT edge-softmax + aggregation: wave-per-node (r4 structure, best measured) -------
__global__ __launch_bounds__(256) void aggregate_kernel(
        const int* __restrict__ row_ptr, const int* __restrict__ ssrc,
        const float* __restrict__ el, const float* __restrict__ er,
        const _Float16* __restrict__ Hh, const float* __restrict__ bias,
        _Float16* __restrict__ zh){
    int wave = threadIdx.x >> 6;
    int lane = threadIdx.x & 63;
    int n = blockIdx.x * 4 + wave;
    int r = blockIdx.y;
    if (n >= NN) return;
    int beg = row_ptr[r * (NN + 1) + n];
    int deg = row_ptr[r * (NN + 1) + n + 1] - beg;
    int h1 = lane & 7;      // pass-1: head
    int slot = lane >> 3;   // pass-1: edge slot
    int h2 = lane >> 3;     // pass-2: head owning channels lane*8..lane*8+7
    const int* sp = ssrc + (size_t)r * EE + beg;
    const float* elp = el + (size_t)r * NN * HH;

    float o[8];
    #pragma unroll
    for (int k = 0; k < 8; k++) o[k] = 0.f;

    if (deg > 0){
        float er1 = er[((size_t)r * NN + n) * HH + h1];
        float m = -INFINITY, den = 0.f;
        // ---- pass 1: per-head online (m, den), 8 edges x 8 heads per iter ----
        for (int e0 = 0; e0 < deg; e0 += 8){
            int e = e0 + slot;
            if (e < deg){
                int s = sp[e];
                float x = elp[(size_t)s * HH + h1] + er1;
                x = (x > 0.f) ? x : 0.2f * x;
                float mn = fmaxf(m, x);
                den = den * __expf(fmaxf(m - mn, -80.f)) + __expf(fmaxf(x - mn, -80.f));
                m = mn;
            }
        }
        #pragma unroll
        for (int st = 8; st < 64; st <<= 1){
            float m2 = __shfl_xor(m, st);
            float d2 = __shfl_xor(den, st);
            float M = fmaxf(m, m2);
            den = den * __expf(fmaxf(m - M, -80.f)) + d2 * __expf(fmaxf(m2 - M, -80.f));
            m = M;
        }
        float m_p = __shfl(m, h2);
        float d_p = __shfl(den, h2);
        float inv = (d_p > 0.f) ? 1.f / d_p : 0.f;
        float er2 = er[((size_t)r * NN + n) * HH + h2];
        const _Float16* Hr = Hh + (size_t)r * NN * DD;
        // ---- pass 2: weight + gather-accumulate, 8 channels/lane ----
        for (int e0 = 0; e0 < deg; e0 += 8){
            int nb = min(8, deg - e0);
            int myv = (lane < nb) ? sp[e0 + lane] : 0;
            for (int j = 0; j < nb; j++){
                int s = __shfl(myv, j);
                float x = elp[(size_t)s * HH + h2] + er2;
                x = (x > 0.f) ? x : 0.2f * x;
                float w = __expf(fmaxf(x - m_p, -80.f)) * inv;
                half8 hv = *reinterpret_cast<const half8*>(Hr + (size_t)s * DD + lane * 8);
                #pragma unroll
                for (int k = 0; k < 8; k++) o[k] += w * (float)hv[k];
            }
        }
    }
    const float* bp = bias + r * DD + lane * 8;
    union { uint4 u; _Float16 h[8]; } pk;
    #pragma unroll
    for (int k = 0; k < 8; k++){
        float v = o[k] + bp[k];
        v = fminf(fmaxf(v, 0.f), 6.f);
        pk.h[k] = (_Float16)v;
    }
    size_t zi = ((size_t)(r * NN + n)) * DD + lane * 8;
    *reinterpret_cast<uint4*>(zh + zi) = pk.u;
}

// ------- w-proj (W1t staged in LDS, two k-halves) + fused beta partial sums -------
#define WKP 264   // padded fp16 stride per col per k-half (256 + 8)
__global__ __launch_bounds__(256) void wproj_kernel(
        const _Float16* __restrict__ Zh, const _Float16* __restrict__ W1t,
        const float* __restrict__ b1, const float* __restrict__ W2,
        float* __restrict__ sums){
    __shared__ _Float16 sW[64 * WKP];
    int t = threadIdx.x;
    int lane = t & 63;
    int wave = t >> 6;
    int l15 = lane & 15;
    int m0 = blockIdx.x * 64 + wave * 16;
    int arow = m0 + l15;
    if (arow >= RR * NN) arow = RR * NN - 1;
    int kg = (lane >> 4) * 8;
    f32x4 acc[4];
    #pragma unroll
    for (int f = 0; f < 4; f++) acc[f] = (f32x4){0.f, 0.f, 0.f, 0.f};
    const _Float16* ap = Zh + (size_t)arow * DD + kg;
    int scol = t >> 2, sseg = t & 3;   // staging map: 64 fp16 per thread per half
    #pragma unroll
    for (int half = 0; half < 2; half++){
        {
            const _Float16* gp = W1t + (size_t)scol * DD + half * 256 + sseg * 64;
            _Float16* lp = &sW[scol * WKP + sseg * 64];
            __syncthreads();   // prior compute done reading LDS
            #pragma unroll
            for (int i = 0; i < 8; i++){
                *reinterpret_cast<uint4*>(lp + i * 8) =
                    *reinterpret_cast<const uint4*>(gp + i * 8);
            }
            __syncthreads();
        }
        #pragma unroll
        for (int kk = 0; kk < 256; kk += 32){
            int k0 = half * 256 + kk;
            half8 af = *reinterpret_cast<const half8*>(ap + k0);
            #pragma unroll
            for (int f = 0; f < 4; f++){
                int col = f * 16 + l15;
                half8 bfr = *reinterpret_cast<const half8*>(&sW[col * WKP + kk + kg]);
                acc[f] = __builtin_amdgcn_mfma_f32_16x16x32_f16(af, bfr, acc[f], 0, 0, 0);
            }
        }
    }
    float s[4] = {0.f, 0.f, 0.f, 0.f};
    #pragma unroll
    for (int f = 0; f < 4; f++){
        int col = f * 16 + l15;
        float bb = b1[col], ww = W2[col];
        #pragma unroll
        for (int g = 0; g < 4; g++) s[g] += tanhf(acc[f][g] + bb) * ww;
    }
    float tot = 0.f;
    #pragma unroll
    for (int g = 0; g < 4; g++){
        s[g] += __shfl_xor(s[g], 1);
        s[g] += __shfl_xor(s[g], 2);
        s[g] += __shfl_xor(s[g], 4);
        s[g] += __shfl_xor(s[g], 8);   // all 16 lanes of group hold row total
        int row = m0 + (lane >> 4) * 4 + g;
        tot += (row < RR * NN) ? s[g] : 0.f;
    }
    // wave covers 16 consecutive rows (20000 % 16 == 0 -> single r per wave)
    tot = tot * 0.0625f;
    tot += __shfl_xor(tot, 16);
    tot += __shfl_xor(tot, 32);
    if (lane == 0 && m0 < RR * NN){
        int rr = m0 / NN;
        atomicAdd(&sums[rr], tot);
    }
}

// ---------------- out = sum_r beta_r * z_r  (beta softmax computed inline) ----------------
__global__ void final_kernel(const _Float16* __restrict__ zh, const float* __restrict__ sums,
                             float* __restrict__ out){
    int idx = blockIdx.x * blockDim.x + threadIdx.x;
    const int cnt = NN * DD / 4;
    if (idx >= cnt) return;
    float m0 = sums[0] * (1.f / NN), m1 = sums[1] * (1.f / NN), m2 = sums[2] * (1.f / NN);
    float mx = fmaxf(m0, fmaxf(m1, m2));
    float e0 = __expf(m0 - mx), e1 = __expf(m1 - mx), e2 = __expf(m2 - mx);
    float inv = 1.f / (e0 + e1 + e2);
    float b0 = e0 * inv, b1 = e1 * inv, b2 = e2 * inv;
    const uint2* zp = reinterpret_cast<const uint2*>(zh);
    const size_t ps = (size_t)NN * DD / 4;
    uint2 a = zp[idx], b = zp[ps + idx], c = zp[2 * ps + idx];
    float2 a0 = up2(a.x), a1 = up2(a.y);
    float2 c0 = up2(b.x), c1 = up2(b.y);
    float2 e0f = up2(c.x), e1f = up2(c.y);
    float4 o;
    o.x = b0 * a0.x + b1 * c0.x + b2 * e0f.x;
    o.y = b0 * a0.y + b1 * c0.y + b2 * e0f.y;
    o.z = b0 * a1.x + b1 * c1.x + b2 * e1f.x;
    o.w = b0 * a1.y + b1 * c1.y + b2 * e1f.y;
    reinterpret_cast<float4*>(out)[idx] = o;
}

extern "C" void kernel_launch(void* const* d_in, const int* in_sizes, int n_in,
                              void* d_out, int out_size, void* d_ws, size_t ws_size,
                              hipStream_t stream){
    const float* feats = (const float*)d_in[0];
    const int*   src   = (const int*)d_in[1];
    const int*   dst   = (const int*)d_in[2];
    const float* W     = (const float*)d_in[3];
    const float* al    = (const float*)d_in[4];
    const float* ar    = (const float*)d_in[5];
    const float* bias  = (const float*)d_in[6];
    const float* W1    = (const float*)d_in[7];
    const float* b1    = (const float*)d_in[8];
    const float* W2    = (const float*)d_in[9];
    float* out = (float*)d_out;

    char* ws = (char*)d_ws;
    size_t off = 0;
    auto alloc = [&](size_t bytes) -> void* {
        void* p = (void*)(ws + off);
        off += (bytes + 255) & ~(size_t)255;
        return p;
    };
    _Float16* Wthi  = (_Float16*)alloc((size_t)RR * DD * FF * 2);
    _Float16* W1t   = (_Float16*)alloc((size_t)OO * DD * 2);
    _Float16* Hh    = (_Float16*)alloc((size_t)RR * NN * DD * 2);
    float*    el    = (float*)alloc((size_t)RR * NN * HH * 4);
    float*    er    = (float*)alloc((size_t)RR * NN * HH * 4);
    _Float16* zh    = (_Float16*)alloc((size_t)RR * NN * DD * 2);
    int*      counts  = (int*)alloc((size_t)RR * NN * 4);      // doubles as cursor
    int*      row_ptr = (int*)alloc((size_t)RR * (NN + 1) * 4);
    int*      ssrc    = (int*)alloc((size_t)RR * EE * 4);
    float*    sums    = (float*)alloc(256);

    transpose_W_kernel<<<RR * 64, 256, 0, stream>>>(W, Wthi);
    prep_small_kernel<<<(RR * NN + 255) / 256, 256, 0, stream>>>(W1, W1t, counts);
    hist_kernel<<<(RR * EE + 255) / 256, 256, 0, stream>>>(dst, counts);
    scan_kernel<<<RR, 1024, 0, stream>>>(counts, row_ptr, sums);
    scatter_kernel<<<(RR * EE + 255) / 256, 256, 0, stream>>>(src, dst, counts, ssrc);
    gemm_h_kernel<<<dim3((NN + BM - 1) / BM, DD / BN, RR), 256, 0, stream>>>(
        feats, Wthi, al, ar, Hh, el, er);
    aggregate_kernel<<<dim3((NN + 3) / 4, RR), 256, 0, stream>>>(
        row_ptr, ssrc, el, er, Hh, bias, zh);
    wproj_kernel<<<(RR * NN + 63) / 64, 256, 0, stream>>>(zh, W1t, b1, W2, sums);
    final_kernel<<<(NN * DD / 4 + 255) / 256, 256, 0, stream>>>(zh, sums, out);
}